// Round 7
// baseline (196.125 us; speedup 1.0000x reference)
//
#include <hip/hip_runtime.h>
#include <math.h>

#define BATCH 512
#define MAXLEN 80
#define LATENT 10
#define HID 64
#define NSTEPS 100
#define DT 0.01f
#define OUTOFF (BATCH * MAXLEN * LATENT)

typedef float v2f __attribute__((ext_vector_type(2)));

__device__ __forceinline__ v2f mkv(float a, float b) { v2f r; r.x = a; r.y = b; return r; }
__device__ __forceinline__ v2f bc(float a) { v2f r; r.x = a; r.y = a; return r; }
__device__ __forceinline__ v2f fma2(v2f a, v2f b, v2f c) { return __builtin_elementwise_fma(a, b, c); }

template <int CTRL>
__device__ __forceinline__ v2f dppadd(v2f x) {
    v2f t;
    t.x = __int_as_float(__builtin_amdgcn_update_dpp(0, __float_as_int(x.x), CTRL, 0xF, 0xF, false));
    t.y = __int_as_float(__builtin_amdgcn_update_dpp(0, __float_as_int(x.y), CTRL, 0xF, 0xF, false));
    return x + t;   // v_pk_add_f32
}
// all-reduce over 8-lane group: xor1, xor2, mirror(xor7) — same tree as R5
__device__ __forceinline__ v2f allsum(v2f x) {
    x = dppadd<0xB1>(x);    // quad_perm [1,0,3,2]
    x = dppadd<0x4E>(x);    // quad_perm [2,3,0,1]
    x = dppadd<0x141>(x);   // row_half_mirror
    return x;
}

// h-pairs += xk * W1[k][slice]
#define HKP(k, xk) { \
    v2f xb = bc(xk); \
    h01 = fma2(xb, w1_##k##_0, h01); h23 = fma2(xb, w1_##k##_1, h23); \
    h45 = fma2(xb, w1_##k##_2, h45); h67 = fma2(xb, w1_##k##_3, h67); }

// ac-pairs += h_q * w2scaled[q][*]
#define W2P(q, hs) { \
    v2f hb = bc(hs); \
    a01 = fma2(hb, w2_##q##_0, a01); a23 = fma2(hb, w2_##q##_1, a23); \
    a45 = fma2(hb, w2_##q##_2, a45); a67 = fma2(hb, w2_##q##_3, a67); \
    a89 = fma2(hb, w2_##q##_4, a89); }

#define DECLW1(k) \
    v2f w1_##k##_0, w1_##k##_1, w1_##k##_2, w1_##k##_3; { \
        const v2f* r_ = (const v2f*)&W1[(k) * HID + j8]; \
        w1_##k##_0 = r_[0]; w1_##k##_1 = r_[1]; w1_##k##_2 = r_[2]; w1_##k##_3 = r_[3]; }

#define DECLW2(q) \
    v2f w2_##q##_0, w2_##q##_1, w2_##q##_2, w2_##q##_3, w2_##q##_4; { \
        const v2f* r_ = (const v2f*)(W2 + (j8 + (q)) * LATENT); \
        w2_##q##_0 = r_[0] * cvt01; w2_##q##_1 = r_[1] * cvt23; \
        w2_##q##_2 = r_[2] * cvt45; w2_##q##_3 = r_[3] * cvt67; \
        w2_##q##_4 = r_[4] * cvt89; }

#define PIN4(a, b, c, d) asm volatile("" : "+v"(a), "+v"(b), "+v"(c), "+v"(d));

__global__ __launch_bounds__(256, 2) void vae_sde_kernel(
    const float* __restrict__ z_mean, const float* __restrict__ z_log_var,
    const float* __restrict__ W1, const float* __restrict__ b1,
    const float* __restrict__ W2, const float* __restrict__ b2,
    const float* __restrict__ noise, float* __restrict__ out)
{
    __shared__ float sMU[32][LATENT];
    __shared__ float sSG[32][LATENT];

    const int tid  = threadIdx.x;
    const int g    = blockIdx.x * 256 + tid;
    const int c    = g >> 3;
    const int lane = tid & 7;
    const int cb   = tid >> 3;
    const int l    = c >> 9;
    const int bb   = c & 511;
    const int base = (bb * MAXLEN + l) * LATENT;
    const bool lp   = (l > 0);
    const bool has2 = (lane < 2);
    const float sqdt = sqrtf(DT);

    float mur0, is0, cw0, icv0, rb2_0, mb0, er0 = 0.f, xsel0;
    float mur1 = 0.f, is1 = 0.f, cw1 = 0.f, icv1 = 0.f, rb2_1 = 0.f,
          mb1 = 0.f, er1 = 0.f, xsel1 = 0.f;

    {
        const int d = lane;
        float zm  = z_mean[base + d];
        float zmp = lp ? z_mean[base - LATENT + d] : 0.f;
        float zv  = z_log_var[base + d];
        float zvp = lp ? z_log_var[base - LATENT + d] : 0.f;
        float mx  = fmaxf(zv, zvp);
        float sg  = mx + log1pf(expf(-fabsf(zv - zvp)));
        float sd  = expf(0.5f * sg);
        float cvv = 0.5f * DT * sd * sd;
        mur0 = zm - zmp; is0 = 1.f / sg; cw0 = sd * sqdt; icv0 = 1.f / cvv;
        rb2_0 = b2[d]; mb0 = fmaf(cvv, rb2_0, mur0 * DT);
        xsel0 = mur0;
        sMU[cb][d] = mur0;
        sSG[cb][d] = sg;
    }
    if (has2) {
        const int d = 8 + lane;
        float zm  = z_mean[base + d];
        float zmp = lp ? z_mean[base - LATENT + d] : 0.f;
        float zv  = z_log_var[base + d];
        float zvp = lp ? z_log_var[base - LATENT + d] : 0.f;
        float mx  = fmaxf(zv, zvp);
        float sg  = mx + log1pf(expf(-fabsf(zv - zvp)));
        float sd  = expf(0.5f * sg);
        float cvv = 0.5f * DT * sd * sd;
        mur1 = zm - zmp; is1 = 1.f / sg; cw1 = sd * sqdt; icv1 = 1.f / cvv;
        rb2_1 = b2[d]; mb1 = fmaf(cvv, rb2_1, mur1 * DT);
        xsel1 = mur1;
        sMU[cb][d] = mur1;
        sSG[cb][d] = sg;
    }
    __syncthreads();

    // replicated per-chain state (packed pairs)
    v2f xt01 = mkv(sMU[cb][0], sMU[cb][1]);
    v2f xt23 = mkv(sMU[cb][2], sMU[cb][3]);
    v2f xt45 = mkv(sMU[cb][4], sMU[cb][5]);
    v2f xt67 = mkv(sMU[cb][6], sMU[cb][7]);
    v2f xt89 = mkv(sMU[cb][8], sMU[cb][9]);
    const v2f cvt01 = mkv(0.5f * DT * expf(sSG[cb][0]), 0.5f * DT * expf(sSG[cb][1]));
    const v2f cvt23 = mkv(0.5f * DT * expf(sSG[cb][2]), 0.5f * DT * expf(sSG[cb][3]));
    const v2f cvt45 = mkv(0.5f * DT * expf(sSG[cb][4]), 0.5f * DT * expf(sSG[cb][5]));
    const v2f cvt67 = mkv(0.5f * DT * expf(sSG[cb][6]), 0.5f * DT * expf(sSG[cb][7]));
    const v2f cvt89 = mkv(0.5f * DT * expf(sSG[cb][8]), 0.5f * DT * expf(sSG[cb][9]));

    const int j8 = lane * 8;
    v2f b1_0, b1_1, b1_2, b1_3;
    { const v2f* r_ = (const v2f*)&b1[j8]; b1_0 = r_[0]; b1_1 = r_[1]; b1_2 = r_[2]; b1_3 = r_[3]; }

    DECLW1(0) DECLW1(1) DECLW1(2) DECLW1(3) DECLW1(4) DECLW1(5)
    DECLW1(6) DECLW1(7) DECLW1(8) DECLW1(9) DECLW1(10)
    DECLW2(0) DECLW2(1) DECLW2(2) DECLW2(3)
    DECLW2(4) DECLW2(5) DECLW2(6) DECLW2(7)

    // pin weights in VGPRs: opaque redefinition -> no remat, no per-step reload
    PIN4(w1_0_0, w1_0_1, w1_0_2, w1_0_3)   PIN4(w1_1_0, w1_1_1, w1_1_2, w1_1_3)
    PIN4(w1_2_0, w1_2_1, w1_2_2, w1_2_3)   PIN4(w1_3_0, w1_3_1, w1_3_2, w1_3_3)
    PIN4(w1_4_0, w1_4_1, w1_4_2, w1_4_3)   PIN4(w1_5_0, w1_5_1, w1_5_2, w1_5_3)
    PIN4(w1_6_0, w1_6_1, w1_6_2, w1_6_3)   PIN4(w1_7_0, w1_7_1, w1_7_2, w1_7_3)
    PIN4(w1_8_0, w1_8_1, w1_8_2, w1_8_3)   PIN4(w1_9_0, w1_9_1, w1_9_2, w1_9_3)
    PIN4(w1_10_0, w1_10_1, w1_10_2, w1_10_3)
    PIN4(b1_0, b1_1, b1_2, b1_3)
    PIN4(w2_0_0, w2_0_1, w2_0_2, w2_0_3)   PIN4(w2_0_4, w2_1_0, w2_1_1, w2_1_2)
    PIN4(w2_1_3, w2_1_4, w2_2_0, w2_2_1)   PIN4(w2_2_2, w2_2_3, w2_2_4, w2_3_0)
    PIN4(w2_3_1, w2_3_2, w2_3_3, w2_3_4)   PIN4(w2_4_0, w2_4_1, w2_4_2, w2_4_3)
    PIN4(w2_4_4, w2_5_0, w2_5_1, w2_5_2)   PIN4(w2_5_3, w2_5_4, w2_6_0, w2_6_1)
    PIN4(w2_6_2, w2_6_3, w2_6_4, w2_7_0)   PIN4(w2_7_1, w2_7_2, w2_7_3, w2_7_4)

    const v2f mk01 = mkv(lane == 0 ? 1.f : 0.f, lane == 1 ? 1.f : 0.f);
    const v2f mk23 = mkv(lane == 2 ? 1.f : 0.f, lane == 3 ? 1.f : 0.f);
    const v2f mk45 = mkv(lane == 4 ? 1.f : 0.f, lane == 5 ? 1.f : 0.f);
    const v2f mk67 = mkv(lane == 6 ? 1.f : 0.f, lane == 7 ? 1.f : 0.f);
    const v2f mk89 = mk01;   // dims 8,9 owned by lanes 0,1

    const float* np0 = noise + ((size_t)l * NSTEPS * BATCH + bb) * LATENT + lane;
    const float* np1 = np0 + (has2 ? 8 : 0);
    float nz0 = np0[0];
    float nz1 = np1[0];

    const v2f zero2 = mkv(0.f, 0.f);

    #pragma unroll 1
    for (int s = 0; s < NSTEPS; ++s) {
        const float cu0 = nz0, cu1 = nz1;
        if (s + 1 < NSTEPS) {
            const size_t off = (size_t)(s + 1) * (BATCH * LATENT);
            nz0 = np0[off];
            nz1 = np1[off];
        }
        const float tt = (float)(l + s) * DT;

        // h = relu([xt, t] @ W1 + b1) — lane's 8-unit slice, packed
        v2f h01 = fma2(bc(xt01.x), w1_0_0, b1_0);
        v2f h23 = fma2(bc(xt01.x), w1_0_1, b1_1);
        v2f h45 = fma2(bc(xt01.x), w1_0_2, b1_2);
        v2f h67 = fma2(bc(xt01.x), w1_0_3, b1_3);
        HKP(1, xt01.y) HKP(2, xt23.x) HKP(3, xt23.y) HKP(4, xt45.x)
        HKP(5, xt45.y) HKP(6, xt67.x) HKP(7, xt67.y) HKP(8, xt89.x)
        HKP(9, xt89.y) HKP(10, tt)
        h01 = __builtin_elementwise_max(h01, zero2);
        h23 = __builtin_elementwise_max(h23, zero2);
        h45 = __builtin_elementwise_max(h45, zero2);
        h67 = __builtin_elementwise_max(h67, zero2);

        // ac partials: cv_d * (W2 h)_d
        v2f a01 = w2_0_0 * bc(h01.x), a23 = w2_0_1 * bc(h01.x);
        v2f a45 = w2_0_2 * bc(h01.x), a67 = w2_0_3 * bc(h01.x);
        v2f a89 = w2_0_4 * bc(h01.x);
        W2P(1, h01.y) W2P(2, h23.x) W2P(3, h23.y) W2P(4, h45.x)
        W2P(5, h45.y) W2P(6, h67.x) W2P(7, h67.y)

        // owner base term: mu*dt + cv*b2 + cw*dW
        const float ob0 = fmaf(cw0, cu0, mb0);
        const float ob1 = fmaf(cw1, cu1, mb1);
        a01 = fma2(mk01, bc(ob0), a01);
        a23 = fma2(mk23, bc(ob0), a23);
        a45 = fma2(mk45, bc(ob0), a45);
        a67 = fma2(mk67, bc(ob0), a67);
        a89 = fma2(mk89, bc(ob1), a89);

        // 8-lane all-reduce -> a* = delta_xt everywhere
        a01 = allsum(a01); a23 = allsum(a23); a45 = allsum(a45);
        a67 = allsum(a67); a89 = allsum(a89);

        // owner extracts its delta (packed mask dot)
        v2f t = a01 * mk01;
        t = fma2(a23, mk23, t);
        t = fma2(a45, mk45, t);
        t = fma2(a67, mk67, t);
        const float ds0 = t.x + t.y;
        v2f t9 = a89 * mk89;
        const float ds1 = t9.x + t9.y;

        // error accumulation at owner
        {
            const float ld = (mur0 - xsel0) * is0;
            const float sc = fmaf(ds0 - ob0, icv0, rb2_0);
            const float df = ld - sc;
            er0 = fmaf(df, df, er0);
            xsel0 += ds0;
        }
        {
            const float ld = (mur1 - xsel1) * is1;
            const float sc = fmaf(ds1 - ob1, icv1, rb2_1);
            const float df = ld - sc;
            er1 = fmaf(df, df, er1);
            xsel1 += ds1;
        }

        // replicated xt update (packed)
        xt01 += a01; xt23 += a23; xt45 += a45; xt67 += a67; xt89 += a89;
    }

    out[base + lane]          = xsel0;
    out[OUTOFF + base + lane] = er0 * (1.0f / NSTEPS);
    if (has2) {
        out[base + 8 + lane]          = xsel1;
        out[OUTOFF + base + 8 + lane] = er1 * (1.0f / NSTEPS);
    }
}

extern "C" void kernel_launch(void* const* d_in, const int* in_sizes, int n_in,
                              void* d_out, int out_size, void* d_ws, size_t ws_size,
                              hipStream_t stream) {
    const float* z_mean    = (const float*)d_in[0];
    const float* z_log_var = (const float*)d_in[1];
    const float* W1 = (const float*)d_in[2];
    const float* b1 = (const float*)d_in[3];
    const float* W2 = (const float*)d_in[4];
    const float* b2 = (const float*)d_in[5];
    const float* noise = (const float*)d_in[6];
    float* out = (float*)d_out;

    vae_sde_kernel<<<dim3(1280), dim3(256), 0, stream>>>(
        z_mean, z_log_var, W1, b1, W2, b2, noise, out);
}

// Round 8
// 195.257 us; speedup vs baseline: 1.0044x; 1.0044x over previous
//
#include <hip/hip_runtime.h>
#include <math.h>

#define BATCH 512
#define MAXLEN 80
#define LATENT 10
#define HID 64
#define NSTEPS 100
#define DT 0.01f
#define OUTOFF (BATCH * MAXLEN * LATENT)

typedef float v2f __attribute__((ext_vector_type(2)));

__device__ __forceinline__ v2f mkv(float a, float b) { v2f r; r.x = a; r.y = b; return r; }
__device__ __forceinline__ v2f bc(float a) { v2f r; r.x = a; r.y = a; return r; }
__device__ __forceinline__ v2f fma2(v2f a, v2f b, v2f c) { return __builtin_elementwise_fma(a, b, c); }

template <int CTRL>
__device__ __forceinline__ v2f dppadd(v2f x) {
    v2f t;
    t.x = __int_as_float(__builtin_amdgcn_update_dpp(0, __float_as_int(x.x), CTRL, 0xF, 0xF, false));
    t.y = __int_as_float(__builtin_amdgcn_update_dpp(0, __float_as_int(x.y), CTRL, 0xF, 0xF, false));
    return x + t;
}
// all-reduce over 8-lane group: xor1, xor2, mirror(xor7)
__device__ __forceinline__ v2f allsum(v2f x) {
    x = dppadd<0xB1>(x);    // quad_perm [1,0,3,2]
    x = dppadd<0x4E>(x);    // quad_perm [2,3,0,1]
    x = dppadd<0x141>(x);   // row_half_mirror
    return x;
}

#define HKP(k, xk) { \
    v2f xb = bc(xk); \
    h01 = fma2(xb, w1_##k##_0, h01); h23 = fma2(xb, w1_##k##_1, h23); \
    h45 = fma2(xb, w1_##k##_2, h45); h67 = fma2(xb, w1_##k##_3, h67); }

#define W2P(q, hs) { \
    v2f hb = bc(hs); \
    a01 = fma2(hb, w2_##q##_0, a01); a23 = fma2(hb, w2_##q##_1, a23); \
    a45 = fma2(hb, w2_##q##_2, a45); a67 = fma2(hb, w2_##q##_3, a67); \
    a89 = fma2(hb, w2_##q##_4, a89); }

#define DECLW1(k) \
    v2f w1_##k##_0, w1_##k##_1, w1_##k##_2, w1_##k##_3; { \
        const v2f* r_ = (const v2f*)&W1[(k) * HID + j8]; \
        w1_##k##_0 = r_[0]; w1_##k##_1 = r_[1]; w1_##k##_2 = r_[2]; w1_##k##_3 = r_[3]; }

#define DECLW2(q) \
    v2f w2_##q##_0, w2_##q##_1, w2_##q##_2, w2_##q##_3, w2_##q##_4; { \
        const v2f* r_ = (const v2f*)(W2 + (j8 + (q)) * LATENT); \
        w2_##q##_0 = r_[0] * cvt01; w2_##q##_1 = r_[1] * cvt23; \
        w2_##q##_2 = r_[2] * cvt45; w2_##q##_3 = r_[3] * cvt67; \
        w2_##q##_4 = r_[4] * cvt89; }

#define PIN4(a, b, c, d) asm volatile("" : "+v"(a), "+v"(b), "+v"(c), "+v"(d));

// Re-pin every iteration: the volatile "+v" redefinition makes the post-asm
// value opaque, so the register allocator CANNOT rematerialize the weight
// loads inside the loop (R7 failure: VGPR=124 -> weights reloaded from L1
// every step, ~2x instruction bloat).
#define PIN_ALL_WEIGHTS \
    PIN4(w1_0_0, w1_0_1, w1_0_2, w1_0_3)   PIN4(w1_1_0, w1_1_1, w1_1_2, w1_1_3) \
    PIN4(w1_2_0, w1_2_1, w1_2_2, w1_2_3)   PIN4(w1_3_0, w1_3_1, w1_3_2, w1_3_3) \
    PIN4(w1_4_0, w1_4_1, w1_4_2, w1_4_3)   PIN4(w1_5_0, w1_5_1, w1_5_2, w1_5_3) \
    PIN4(w1_6_0, w1_6_1, w1_6_2, w1_6_3)   PIN4(w1_7_0, w1_7_1, w1_7_2, w1_7_3) \
    PIN4(w1_8_0, w1_8_1, w1_8_2, w1_8_3)   PIN4(w1_9_0, w1_9_1, w1_9_2, w1_9_3) \
    PIN4(w1_10_0, w1_10_1, w1_10_2, w1_10_3) \
    PIN4(b1_0, b1_1, b1_2, b1_3) \
    PIN4(w2_0_0, w2_0_1, w2_0_2, w2_0_3)   PIN4(w2_0_4, w2_1_0, w2_1_1, w2_1_2) \
    PIN4(w2_1_3, w2_1_4, w2_2_0, w2_2_1)   PIN4(w2_2_2, w2_2_3, w2_2_4, w2_3_0) \
    PIN4(w2_3_1, w2_3_2, w2_3_3, w2_3_4)   PIN4(w2_4_0, w2_4_1, w2_4_2, w2_4_3) \
    PIN4(w2_4_4, w2_5_0, w2_5_1, w2_5_2)   PIN4(w2_5_3, w2_5_4, w2_6_0, w2_6_1) \
    PIN4(w2_6_2, w2_6_3, w2_6_4, w2_7_0)   PIN4(w2_7_1, w2_7_2, w2_7_3, w2_7_4)

__global__ __launch_bounds__(256, 2) void vae_sde_kernel(
    const float* __restrict__ z_mean, const float* __restrict__ z_log_var,
    const float* __restrict__ W1, const float* __restrict__ b1,
    const float* __restrict__ W2, const float* __restrict__ b2,
    const float* __restrict__ noise, float* __restrict__ out)
{
    __shared__ float sMU[32][LATENT];
    __shared__ float sSG[32][LATENT];

    const int tid  = threadIdx.x;
    const int g    = blockIdx.x * 256 + tid;
    const int c    = g >> 3;
    const int lane = tid & 7;
    const int cb   = tid >> 3;
    const int l    = c >> 9;
    const int bb   = c & 511;
    const int base = (bb * MAXLEN + l) * LATENT;
    const bool lp   = (l > 0);
    const bool has2 = (lane < 2);
    const float sqdt = sqrtf(DT);

    float mur0, is0, cw0, icv0, rb2_0, mb0, er0 = 0.f, xsel0;
    float mur1 = 0.f, is1 = 0.f, cw1 = 0.f, icv1 = 0.f, rb2_1 = 0.f,
          mb1 = 0.f, er1 = 0.f, xsel1 = 0.f;

    {
        const int d = lane;
        float zm  = z_mean[base + d];
        float zmp = lp ? z_mean[base - LATENT + d] : 0.f;
        float zv  = z_log_var[base + d];
        float zvp = lp ? z_log_var[base - LATENT + d] : 0.f;
        float mx  = fmaxf(zv, zvp);
        float sg  = mx + log1pf(expf(-fabsf(zv - zvp)));
        float sd  = expf(0.5f * sg);
        float cvv = 0.5f * DT * sd * sd;
        mur0 = zm - zmp; is0 = 1.f / sg; cw0 = sd * sqdt; icv0 = 1.f / cvv;
        rb2_0 = b2[d]; mb0 = fmaf(cvv, rb2_0, mur0 * DT);
        xsel0 = mur0;
        sMU[cb][d] = mur0;
        sSG[cb][d] = sg;
    }
    if (has2) {
        const int d = 8 + lane;
        float zm  = z_mean[base + d];
        float zmp = lp ? z_mean[base - LATENT + d] : 0.f;
        float zv  = z_log_var[base + d];
        float zvp = lp ? z_log_var[base - LATENT + d] : 0.f;
        float mx  = fmaxf(zv, zvp);
        float sg  = mx + log1pf(expf(-fabsf(zv - zvp)));
        float sd  = expf(0.5f * sg);
        float cvv = 0.5f * DT * sd * sd;
        mur1 = zm - zmp; is1 = 1.f / sg; cw1 = sd * sqdt; icv1 = 1.f / cvv;
        rb2_1 = b2[d]; mb1 = fmaf(cvv, rb2_1, mur1 * DT);
        xsel1 = mur1;
        sMU[cb][d] = mur1;
        sSG[cb][d] = sg;
    }
    __syncthreads();

    v2f xt01 = mkv(sMU[cb][0], sMU[cb][1]);
    v2f xt23 = mkv(sMU[cb][2], sMU[cb][3]);
    v2f xt45 = mkv(sMU[cb][4], sMU[cb][5]);
    v2f xt67 = mkv(sMU[cb][6], sMU[cb][7]);
    v2f xt89 = mkv(sMU[cb][8], sMU[cb][9]);
    const v2f cvt01 = mkv(0.5f * DT * expf(sSG[cb][0]), 0.5f * DT * expf(sSG[cb][1]));
    const v2f cvt23 = mkv(0.5f * DT * expf(sSG[cb][2]), 0.5f * DT * expf(sSG[cb][3]));
    const v2f cvt45 = mkv(0.5f * DT * expf(sSG[cb][4]), 0.5f * DT * expf(sSG[cb][5]));
    const v2f cvt67 = mkv(0.5f * DT * expf(sSG[cb][6]), 0.5f * DT * expf(sSG[cb][7]));
    const v2f cvt89 = mkv(0.5f * DT * expf(sSG[cb][8]), 0.5f * DT * expf(sSG[cb][9]));

    const int j8 = lane * 8;
    v2f b1_0, b1_1, b1_2, b1_3;
    { const v2f* r_ = (const v2f*)&b1[j8]; b1_0 = r_[0]; b1_1 = r_[1]; b1_2 = r_[2]; b1_3 = r_[3]; }

    DECLW1(0) DECLW1(1) DECLW1(2) DECLW1(3) DECLW1(4) DECLW1(5)
    DECLW1(6) DECLW1(7) DECLW1(8) DECLW1(9) DECLW1(10)
    DECLW2(0) DECLW2(1) DECLW2(2) DECLW2(3)
    DECLW2(4) DECLW2(5) DECLW2(6) DECLW2(7)

    const v2f mk01 = mkv(lane == 0 ? 1.f : 0.f, lane == 1 ? 1.f : 0.f);
    const v2f mk23 = mkv(lane == 2 ? 1.f : 0.f, lane == 3 ? 1.f : 0.f);
    const v2f mk45 = mkv(lane == 4 ? 1.f : 0.f, lane == 5 ? 1.f : 0.f);
    const v2f mk67 = mkv(lane == 6 ? 1.f : 0.f, lane == 7 ? 1.f : 0.f);
    const v2f mk89 = mk01;

    const float* np0 = noise + ((size_t)l * NSTEPS * BATCH + bb) * LATENT + lane;
    const float* np1 = np0 + (has2 ? 8 : 0);
    float nz0 = np0[0];
    float nz1 = np1[0];

    const v2f zero2 = mkv(0.f, 0.f);

    #pragma unroll 1
    for (int s = 0; s < NSTEPS; ++s) {
        PIN_ALL_WEIGHTS   // emits nothing; forces weights register-resident

        const float cu0 = nz0, cu1 = nz1;
        if (s + 1 < NSTEPS) {
            const size_t off = (size_t)(s + 1) * (BATCH * LATENT);
            nz0 = np0[off];
            nz1 = np1[off];
        }
        const float tt = (float)(l + s) * DT;

        v2f h01 = fma2(bc(xt01.x), w1_0_0, b1_0);
        v2f h23 = fma2(bc(xt01.x), w1_0_1, b1_1);
        v2f h45 = fma2(bc(xt01.x), w1_0_2, b1_2);
        v2f h67 = fma2(bc(xt01.x), w1_0_3, b1_3);
        HKP(1, xt01.y) HKP(2, xt23.x) HKP(3, xt23.y) HKP(4, xt45.x)
        HKP(5, xt45.y) HKP(6, xt67.x) HKP(7, xt67.y) HKP(8, xt89.x)
        HKP(9, xt89.y) HKP(10, tt)
        h01 = __builtin_elementwise_max(h01, zero2);
        h23 = __builtin_elementwise_max(h23, zero2);
        h45 = __builtin_elementwise_max(h45, zero2);
        h67 = __builtin_elementwise_max(h67, zero2);

        v2f a01 = w2_0_0 * bc(h01.x), a23 = w2_0_1 * bc(h01.x);
        v2f a45 = w2_0_2 * bc(h01.x), a67 = w2_0_3 * bc(h01.x);
        v2f a89 = w2_0_4 * bc(h01.x);
        W2P(1, h01.y) W2P(2, h23.x) W2P(3, h23.y) W2P(4, h45.x)
        W2P(5, h45.y) W2P(6, h67.x) W2P(7, h67.y)

        const float ob0 = fmaf(cw0, cu0, mb0);
        const float ob1 = fmaf(cw1, cu1, mb1);
        a01 = fma2(mk01, bc(ob0), a01);
        a23 = fma2(mk23, bc(ob0), a23);
        a45 = fma2(mk45, bc(ob0), a45);
        a67 = fma2(mk67, bc(ob0), a67);
        a89 = fma2(mk89, bc(ob1), a89);

        a01 = allsum(a01); a23 = allsum(a23); a45 = allsum(a45);
        a67 = allsum(a67); a89 = allsum(a89);

        v2f t = a01 * mk01;
        t = fma2(a23, mk23, t);
        t = fma2(a45, mk45, t);
        t = fma2(a67, mk67, t);
        const float ds0 = t.x + t.y;
        v2f t9 = a89 * mk89;
        const float ds1 = t9.x + t9.y;

        {
            const float ld = (mur0 - xsel0) * is0;
            const float sc = fmaf(ds0 - ob0, icv0, rb2_0);
            const float df = ld - sc;
            er0 = fmaf(df, df, er0);
            xsel0 += ds0;
        }
        {
            const float ld = (mur1 - xsel1) * is1;
            const float sc = fmaf(ds1 - ob1, icv1, rb2_1);
            const float df = ld - sc;
            er1 = fmaf(df, df, er1);
            xsel1 += ds1;
        }

        xt01 += a01; xt23 += a23; xt45 += a45; xt67 += a67; xt89 += a89;
    }

    out[base + lane]          = xsel0;
    out[OUTOFF + base + lane] = er0 * (1.0f / NSTEPS);
    if (has2) {
        out[base + 8 + lane]          = xsel1;
        out[OUTOFF + base + 8 + lane] = er1 * (1.0f / NSTEPS);
    }
}

extern "C" void kernel_launch(void* const* d_in, const int* in_sizes, int n_in,
                              void* d_out, int out_size, void* d_ws, size_t ws_size,
                              hipStream_t stream) {
    const float* z_mean    = (const float*)d_in[0];
    const float* z_log_var = (const float*)d_in[1];
    const float* W1 = (const float*)d_in[2];
    const float* b1 = (const float*)d_in[3];
    const float* W2 = (const float*)d_in[4];
    const float* b2 = (const float*)d_in[5];
    const float* noise = (const float*)d_in[6];
    float* out = (float*)d_out;

    vae_sde_kernel<<<dim3(1280), dim3(256), 0, stream>>>(
        z_mean, z_log_var, W1, b1, W2, b2, noise, out);
}